// Round 8
// baseline (693.176 us; speedup 1.0000x reference)
//
#include <hip/hip_runtime.h>
#include <hip/hip_bf16.h>

#define T_ 4
#define B_ 8
#define S_ 1024
#define D_ 768
#define BS_ (B_*S_)            // 8192
#define M_ (T_*B_*S_)          // 32768
#define BSD_ (B_*S_*D_)        // 6291456
#define LN_EPS 1e-5f
#define TAU 4e-5f

typedef unsigned short u16;
typedef unsigned char u8;
typedef unsigned int u32;
typedef unsigned long long u64;
typedef __bf16 bf16x8 __attribute__((ext_vector_type(8)));
typedef float f32x4 __attribute__((ext_vector_type(4)));

// ---- IF over x -> bitmask spikes + bf16 spikes, bit-exact vs np ----
__global__ __launch_bounds__(768)
void k_if_mask(const float* __restrict__ x, u64* __restrict__ Am, u16* __restrict__ Ab) {
    int bs = blockIdx.x;           // 8192 blocks
    int d = threadIdx.x;           // 768 threads
    int wv = d >> 6, lane = d & 63;
    float v = 0.f;
    for (int t = 0; t < T_; ++t) {
        v += x[(size_t)t * BSD_ + (size_t)bs * D_ + d];
        bool s = (v >= 1.0f);
        u64 m = __ballot(s);
        if (lane == 0) Am[((size_t)t * 12 + wv) * BS_ + bs] = m;
        Ab[(size_t)t * BSD_ + (size_t)bs * D_ + d] = s ? 0x3F80 : 0;
        if (s) v = 0.f;
    }
}

// ---- weight convert: Bt layout [N][K], hi/lo split for q/k/v; bf16 for wo ----
__global__ void k_wconv(const float* __restrict__ wq, const float* __restrict__ wk,
                        const float* __restrict__ wv, const float* __restrict__ wo,
                        u16* __restrict__ Whi, u16* __restrict__ Wlo, u16* __restrict__ Wo) {
    int idx = blockIdx.x * 256 + threadIdx.x;       // 9216 blocks
    int mat = idx / (D_ * D_);
    int r = idx % (D_ * D_);
    int n = r / D_;
    int k = r % D_;
    const float* src = (mat == 0) ? wq : (mat == 1) ? wk : (mat == 2) ? wv : wo;
    float w = src[k * D_ + n];
    __bf16 hi = (__bf16)w;
    u16 uhi = __builtin_bit_cast(u16, hi);
    if (mat == 3) { Wo[r] = uhi; return; }
    float lo = w - (float)hi;
    u16 ulo = __builtin_bit_cast(u16, (__bf16)lo);
    Whi[(size_t)mat * D_ * D_ + r] = uhi;
    Wlo[(size_t)mat * D_ * D_ + r] = ulo;
}

// ---- MFMA GEMM: C = A @ Bhi^T (+ A @ Blo^T if NMATS==2), single K pass ----
__device__ __forceinline__ void gload16(const void* g, void* l) {
    __builtin_amdgcn_global_load_lds(
        (const __attribute__((address_space(1))) unsigned int*)g,
        (__attribute__((address_space(3))) unsigned int*)l, 16, 0, 0);
}

template<int NMATS>
__global__ __launch_bounds__(256)
void k_gemm(const u16* __restrict__ A, const u16* __restrict__ Bhi,
            const u16* __restrict__ Blo, float* __restrict__ C, int ntn, int N) {
    __shared__ __align__(16) u16 As[128 * 32];
    __shared__ __align__(16) u16 Bh[128 * 32];
    __shared__ __align__(16) u16 Bl[128 * 32];
    int bid = blockIdx.x;
    bid = (bid & 7) * (gridDim.x >> 3) + (bid >> 3);   // XCD chunked swizzle (grid%8==0)
    int bn = bid % ntn, bm = bid / ntn;
    int tid = threadIdx.x;
    int l = tid & 63, w = tid >> 6;
    int wr = w >> 1, wc = w & 1;
    int lan16 = l & 15, kh = l >> 4;

    f32x4 acc[4][4];
    #pragma unroll
    for (int m = 0; m < 4; ++m)
        #pragma unroll
        for (int n = 0; n < 4; ++n)
            #pragma unroll
            for (int r = 0; r < 4; ++r) acc[m][n][r] = 0.f;

    int arow = bm * 128 + (tid >> 2);
    int brow = bn * 128 + (tid >> 2);
    int colb = (((tid & 3) ^ ((tid >> 3) & 3)) * 8);   // pre-swizzled source chunk
    char* ldsA = (char*)As + ((tid >> 6) << 10);
    char* ldsBh = (char*)Bh + ((tid >> 6) << 10);
    char* ldsBl = (char*)Bl + ((tid >> 6) << 10);

    int khs16 = (kh ^ ((lan16 >> 1) & 3)) << 4;        // swizzled read chunk byte
    int aoff[4], boff[4];
    #pragma unroll
    for (int m = 0; m < 4; ++m) aoff[m] = (wr * 64 + m * 16 + lan16) * 64 + khs16;
    #pragma unroll
    for (int n = 0; n < 4; ++n) boff[n] = (wc * 64 + n * 16 + lan16) * 64 + khs16;

    for (int kk = 0; kk < 768; kk += 32) {
        gload16(A   + (size_t)(arow     ) * 768 + kk + colb, ldsA);
        gload16(A   + (size_t)(arow + 64) * 768 + kk + colb, ldsA + 4096);
        gload16(Bhi + (size_t)(brow     ) * 768 + kk + colb, ldsBh);
        gload16(Bhi + (size_t)(brow + 64) * 768 + kk + colb, ldsBh + 4096);
        if (NMATS == 2) {
            gload16(Blo + (size_t)(brow     ) * 768 + kk + colb, ldsBl);
            gload16(Blo + (size_t)(brow + 64) * 768 + kk + colb, ldsBl + 4096);
        }
        __syncthreads();
        bf16x8 af[4], bh[4], bl[4];
        #pragma unroll
        for (int m = 0; m < 4; ++m)
            af[m] = *(const bf16x8*)((const char*)As + aoff[m]);
        #pragma unroll
        for (int n = 0; n < 4; ++n) {
            bh[n] = *(const bf16x8*)((const char*)Bh + boff[n]);
            if (NMATS == 2) bl[n] = *(const bf16x8*)((const char*)Bl + boff[n]);
        }
        #pragma unroll
        for (int m = 0; m < 4; ++m)
            #pragma unroll
            for (int n = 0; n < 4; ++n) {
                acc[m][n] = __builtin_amdgcn_mfma_f32_16x16x32_bf16(af[m], bh[n], acc[m][n], 0, 0, 0);
                if (NMATS == 2)
                    acc[m][n] = __builtin_amdgcn_mfma_f32_16x16x32_bf16(af[m], bl[n], acc[m][n], 0, 0, 0);
            }
        __syncthreads();
    }
    #pragma unroll
    for (int m = 0; m < 4; ++m)
        #pragma unroll
        for (int n = 0; n < 4; ++n)
            #pragma unroll
            for (int r = 0; r < 4; ++r) {
                int crow = bm * 128 + wr * 64 + m * 16 + kh * 4 + r;
                int ccol = bn * 128 + wc * 64 + n * 16 + lan16;
                C[(size_t)crow * N + ccol] = acc[m][n][r];
            }
}

// ---- LN (f64 mean/var) + IF -> u8 spikes; flagged rows -> compact list ----
__global__ __launch_bounds__(256)
void k_lnif(const float* __restrict__ Y, const float* __restrict__ g,
            const float* __restrict__ bt, u8* __restrict__ Sp,
            int* __restrict__ rowlist, int* __restrict__ cnt, int mat) {
    #pragma clang fp contract(off)
    int row = blockIdx.x * 4 + (threadIdx.x >> 6);   // (b,s) 0..8191
    int lane = threadIdx.x & 63;
    float v[12];
    #pragma unroll
    for (int i = 0; i < 12; ++i) v[i] = 0.f;
    float gv[12], bv[12];
    #pragma unroll
    for (int i = 0; i < 12; ++i) { gv[i] = g[lane + 64*i]; bv[i] = bt[lane + 64*i]; }
    bool fl = false;
    for (int t = 0; t < T_; ++t) {
        size_t base = ((size_t)t * BS_ + row) * D_;
        float xv[12];
        double s = 0.0;
        #pragma unroll
        for (int i = 0; i < 12; ++i) { xv[i] = Y[base + lane + 64*i]; s += (double)xv[i]; }
        #pragma unroll
        for (int o = 1; o < 64; o <<= 1) s += __shfl_xor(s, o, 64);
        s = __shfl(s, 0, 64);
        float m = (float)(s / 768.0);
        float d[12];
        double q = 0.0;
        #pragma unroll
        for (int i = 0; i < 12; ++i) { d[i] = xv[i] - m; float sq = d[i]*d[i]; q += (double)sq; }
        #pragma unroll
        for (int o = 1; o < 64; o <<= 1) q += __shfl_xor(q, o, 64);
        q = __shfl(q, 0, 64);
        float var = (float)(q / 768.0);
        float inv = 1.0f / __fsqrt_rn(var + LN_EPS);
        #pragma unroll
        for (int i = 0; i < 12; ++i) {
            float yn = ((d[i] * inv) * gv[i]) + bv[i];
            v[i] += yn;
            fl = fl || (fabsf(v[i] - 1.0f) < TAU);
            bool sp = (v[i] >= 1.0f);
            Sp[base + lane + 64*i] = sp ? (u8)1 : (u8)0;
            if (sp) v[i] = 0.f;
        }
    }
    u64 bal = __ballot(fl);
    if (lane == 0 && bal != 0ull) {
        int slot = atomicAdd(cnt + mat, 1);
        rowlist[mat * BS_ + slot] = row;
    }
}

// ---- f64 block reduce over 192 threads (3 waves) ----
__device__ __forceinline__ double bred192(double v, double* red) {
    #pragma unroll
    for (int o = 1; o < 64; o <<= 1) v += __shfl_xor(v, o, 64);
    int lane = threadIdx.x & 63, w = threadIdx.x >> 6;
    __syncthreads();
    if (lane == 0) red[w] = v;
    __syncthreads();
    return red[0] + red[1] + red[2];
}

// ---- row repair, union walk, 2 rows/block ----
// Per (row,t) arithmetic identical to the green round-6 repair: ascending-k
// sequential f32 adds (np sgemm order), f64 LN, f32 chain. The union list +
// 8-bit (row,t) tag shares each weight float4 across up to 8 chains (4x fewer
// weight reads than per-t walks; 2x more via row pairing).
__global__ __launch_bounds__(192)
void k_repairU(const u64* __restrict__ Am,
               const float* __restrict__ wq, const float* __restrict__ wk,
               const float* __restrict__ wv,
               const float* __restrict__ gq, const float* __restrict__ bq,
               const float* __restrict__ gk, const float* __restrict__ bk,
               const float* __restrict__ gv, const float* __restrict__ bv,
               u8* __restrict__ Qs, u8* __restrict__ Ks, u8* __restrict__ Vs,
               const int* __restrict__ rowlist, const int* __restrict__ cnt) {
    #pragma clang fp contract(off)
    int mat = blockIdx.y;
    int nf = cnt[mat];
    int base = blockIdx.x * 2;
    if (base >= nf) return;
    const float* W = (mat == 0) ? wq : (mat == 1) ? wk : wv;
    const float* g = (mat == 0) ? gq : (mat == 1) ? gk : gv;
    const float* bb = (mat == 0) ? bq : (mat == 1) ? bk : bv;
    u8* Sp = (mat == 0) ? Qs : (mat == 1) ? Ks : Vs;
    const float4* Wv4 = (const float4*)W;

    __shared__ u64 mks[2][4][12];
    __shared__ u64 uni[12];
    __shared__ int pops[12];
    __shared__ u16 idxs[768];
    __shared__ u8 tms[768];
    __shared__ int cnt_s;
    __shared__ double red[3];
    __shared__ int rows_s[2];

    int tid = threadIdx.x;
    if (tid < 2) {
        int e = base + tid;
        rows_s[tid] = rowlist[mat * BS_ + (e < nf ? e : nf - 1)];
    }
    __syncthreads();
    int r0 = rows_s[0], r1 = rows_s[1];
    if (tid < 96) {
        int rr = tid / 48, rem = tid % 48;
        int t = rem / 12, kw = rem % 12;
        int row = rr ? r1 : r0;
        mks[rr][t][kw] = Am[((size_t)t * 12 + kw) * BS_ + row];
    }
    __syncthreads();
    if (tid < 12) {
        u64 u = 0;
        #pragma unroll
        for (int rr = 0; rr < 2; ++rr)
            #pragma unroll
            for (int t = 0; t < 4; ++t) u |= mks[rr][t][tid];
        uni[tid] = u;
        pops[tid] = __popcll(u);
    }
    __syncthreads();
    if (tid < 12) {
        int off = 0;
        for (int j = 0; j < tid; ++j) off += pops[j];
        u64 u = uni[tid];
        int kb0 = tid * 64;
        while (u) {
            int kb = __builtin_ctzll(u);
            u &= u - 1;
            u8 tm = 0;
            #pragma unroll
            for (int rr = 0; rr < 2; ++rr)
                #pragma unroll
                for (int t = 0; t < 4; ++t)
                    tm |= (u8)(((mks[rr][t][tid] >> kb) & 1ull) << (rr * 4 + t));
            idxs[off] = (u16)(kb0 + kb);
            tms[off] = tm;
            ++off;
        }
        if (tid == 11) cnt_s = off;
    }
    __syncthreads();
    int cu = cnt_s;

    int c = tid;                      // float4 col index: cols 4c..4c+3
    float4 gd = ((const float4*)g)[c];
    float4 bd = ((const float4*)bb)[c];

    float y[2][4][4];                 // [row][t][col4]
    #pragma unroll
    for (int rr = 0; rr < 2; ++rr)
        #pragma unroll
        for (int t = 0; t < 4; ++t)
            #pragma unroll
            for (int j = 0; j < 4; ++j) y[rr][t][j] = 0.f;

    #pragma unroll 2
    for (int i = 0; i < cu; ++i) {
        int k = idxs[i];
        int tm = tms[i];
        float4 w = Wv4[(size_t)k * 192 + c];
        if (tm & 1)   { y[0][0][0] += w.x; y[0][0][1] += w.y; y[0][0][2] += w.z; y[0][0][3] += w.w; }
        if (tm & 2)   { y[0][1][0] += w.x; y[0][1][1] += w.y; y[0][1][2] += w.z; y[0][1][3] += w.w; }
        if (tm & 4)   { y[0][2][0] += w.x; y[0][2][1] += w.y; y[0][2][2] += w.z; y[0][2][3] += w.w; }
        if (tm & 8)   { y[0][3][0] += w.x; y[0][3][1] += w.y; y[0][3][2] += w.z; y[0][3][3] += w.w; }
        if (tm & 16)  { y[1][0][0] += w.x; y[1][0][1] += w.y; y[1][0][2] += w.z; y[1][0][3] += w.w; }
        if (tm & 32)  { y[1][1][0] += w.x; y[1][1][1] += w.y; y[1][1][2] += w.z; y[1][1][3] += w.w; }
        if (tm & 64)  { y[1][2][0] += w.x; y[1][2][1] += w.y; y[1][2][2] += w.z; y[1][2][3] += w.w; }
        if (tm & 128) { y[1][3][0] += w.x; y[1][3][1] += w.y; y[1][3][2] += w.z; y[1][3][3] += w.w; }
    }

    // f64 LN per (row,t), then f32 IF chains (round-6 arithmetic)
    float mean_[2][4], inv_[2][4];
    #pragma unroll
    for (int rr = 0; rr < 2; ++rr)
        #pragma unroll
        for (int t = 0; t < 4; ++t) {
            double s = (double)y[rr][t][0] + (double)y[rr][t][1]
                     + (double)y[rr][t][2] + (double)y[rr][t][3];
            double stot = bred192(s, red);
            float mean = (float)(stot / 768.0);
            float d0 = y[rr][t][0] - mean, d1 = y[rr][t][1] - mean;
            float d2 = y[rr][t][2] - mean, d3 = y[rr][t][3] - mean;
            double q = (double)(d0*d0) + (double)(d1*d1)
                     + (double)(d2*d2) + (double)(d3*d3);
            double qtot = bred192(q, red);
            float var = (float)(qtot / 768.0);
            mean_[rr][t] = mean;
            inv_[rr][t] = 1.0f / __fsqrt_rn(var + LN_EPS);
        }

    #pragma unroll
    for (int rr = 0; rr < 2; ++rr) {
        int row = rr ? r1 : r0;
        uchar4 o4[4];
        #pragma unroll
        for (int j = 0; j < 4; ++j) {
            float gj = (j == 0) ? gd.x : (j == 1) ? gd.y : (j == 2) ? gd.z : gd.w;
            float bj = (j == 0) ? bd.x : (j == 1) ? bd.y : (j == 2) ? bd.z : bd.w;
            float v = 0.f;
            #pragma unroll
            for (int t = 0; t < 4; ++t) {
                float d = y[rr][t][j] - mean_[rr][t];
                float yn = ((d * inv_[rr][t]) * gj) + bj;
                v += yn;
                bool sp = (v >= 1.0f);
                u8 sb = sp ? (u8)1 : (u8)0;
                if (j == 0) o4[t].x = sb;
                if (j == 1) o4[t].y = sb;
                if (j == 2) o4[t].z = sb;
                if (j == 3) o4[t].w = sb;
                if (sp) v = 0.f;
            }
        }
        #pragma unroll
        for (int t = 0; t < 4; ++t)
            *(uchar4*)(Sp + ((size_t)t * BS_ + row) * D_ + c * 4) = o4[t];
    }
}

// ---- QK column-dot over S (exact integer counts) ----
__global__ void k_qkred(const u8* __restrict__ Q, const u8* __restrict__ K,
                        float* __restrict__ QK) {
    int bid = blockIdx.x;           // 1024 blocks, 192 threads
    int sg = bid & 31, tb = bid >> 5;
    int tid = threadIdx.x;
    int c4 = tid * 4;
    size_t base = (size_t)tb * S_ * D_ + (size_t)sg * 32 * D_;
    int acc[4] = {0, 0, 0, 0};
    for (int s = 0; s < 32; ++s) {
        uchar4 q = *(const uchar4*)(Q + base + (size_t)s * D_ + c4);
        uchar4 k = *(const uchar4*)(K + base + (size_t)s * D_ + c4);
        acc[0] += q.x & k.x; acc[1] += q.y & k.y; acc[2] += q.z & k.z; acc[3] += q.w & k.w;
    }
    float* dst = QK + (size_t)tb * D_ + c4;
    #pragma unroll
    for (int j = 0; j < 4; ++j) atomicAdd(dst + j, (float)acc[j]);
}

// ---- IF over T on QK counts (integer-exact) ----
__global__ void k_qkif(const float* __restrict__ QK, u8* __restrict__ QKs) {
    int i = blockIdx.x * 256 + threadIdx.x;     // 24 blocks
    float v = 0.f;
    for (int t = 0; t < T_; ++t) {
        v += QK[t * (B_ * D_) + i];
        bool s = (v >= 1.0f);
        QKs[t * (B_ * D_) + i] = s ? 1 : 0;
        if (s) v = 0.f;
    }
}

// ---- QKV = V * QKs -> bf16 {0,1} ----
__global__ void k_qkv(const u8* __restrict__ V, const u8* __restrict__ QKs,
                      u16* __restrict__ O) {
    size_t e = ((size_t)blockIdx.x * 256 + threadIdx.x) * 4;    // 24576 blocks
    uchar4 v = *(const uchar4*)(V + e);
    size_t d = e % D_;
    size_t b = (e / ((size_t)S_ * D_)) % B_;
    size_t t = e / BSD_;
    uchar4 qk = *(const uchar4*)(QKs + t * (B_ * D_) + b * D_ + d);
    ushort4 o;
    o.x = (v.x & qk.x) ? 0x3F80 : 0;
    o.y = (v.y & qk.y) ? 0x3F80 : 0;
    o.z = (v.z & qk.z) ? 0x3F80 : 0;
    o.w = (v.w & qk.w) ? 0x3F80 : 0;
    *(ushort4*)(O + e) = o;
}

// ---- block reduction helper (final LN only; tolerance loose) ----
__device__ __forceinline__ float block_sum(float v, float* red) {
    #pragma unroll
    for (int o = 32; o > 0; o >>= 1) v += __shfl_down(v, o, 64);
    int lane = threadIdx.x & 63, w = threadIdx.x >> 6;
    __syncthreads();
    if (lane == 0) red[w] = v;
    __syncthreads();
    return (red[0] + red[1]) + (red[2] + red[3]);
}

__global__ __launch_bounds__(256)
void k_lnfinal(const float* __restrict__ Y, const float* __restrict__ g,
               const float* __restrict__ bt, float* __restrict__ out) {
    #pragma clang fp contract(off)
    __shared__ float red[4];
    size_t row = (size_t)blockIdx.x * D_;       // 32768 rows
    int tid = threadIdx.x;
    float y[3];
    float s = 0.f;
    #pragma unroll
    for (int j = 0; j < 3; ++j) { y[j] = Y[row + tid + j * 256]; s += y[j]; }
    float mean = block_sum(s, red) / 768.0f;
    float q = 0.f;
    #pragma unroll
    for (int j = 0; j < 3; ++j) { float d = y[j] - mean; q += d * d; }
    float var = block_sum(q, red) / 768.0f;
    float inv = 1.0f / __fsqrt_rn(var + LN_EPS);
    #pragma unroll
    for (int j = 0; j < 3; ++j) {
        int c = tid + j * 256;
        out[row + c] = (y[j] - mean) * inv * g[c] + bt[c];
    }
}

extern "C" void kernel_launch(void* const* d_in, const int* in_sizes, int n_in,
                              void* d_out, int out_size, void* d_ws, size_t ws_size,
                              hipStream_t stream) {
    const float* x  = (const float*)d_in[0];
    const float* wq = (const float*)d_in[1];
    const float* wk = (const float*)d_in[2];
    const float* wv = (const float*)d_in[3];
    const float* wo = (const float*)d_in[4];
    const float* gq = (const float*)d_in[5];
    const float* bq = (const float*)d_in[6];
    const float* gk = (const float*)d_in[7];
    const float* bk = (const float*)d_in[8];
    const float* gv = (const float*)d_in[9];
    const float* bv = (const float*)d_in[10];
    const float* go = (const float*)d_in[11];
    const float* bo = (const float*)d_in[12];
    float* out = (float*)d_out;

    char* ws = (char*)d_ws;
    size_t off = 0;
    auto alloc = [&](size_t bytes) -> void* {
        void* p = ws + off;
        off += (bytes + 255) & ~(size_t)255;
        return p;
    };
    u64* Am    = (u64*)alloc((size_t)T_ * 12 * BS_ * 8);     // 3 MB bitmasks
    u16* Ab    = (u16*)alloc((size_t)M_ * D_ * 2);           // 48 MB bf16 spikes / reused for QKV
    float* Y   = (float*)alloc((size_t)M_ * D_ * 4);         // 96 MB GEMM out
    u8* Qs     = (u8*)alloc((size_t)M_ * D_);
    u8* Ks     = (u8*)alloc((size_t)M_ * D_);
    u8* Vs     = (u8*)alloc((size_t)M_ * D_);
    u16* Whi   = (u16*)alloc((size_t)3 * D_ * D_ * 2);
    u16* Wlo   = (u16*)alloc((size_t)3 * D_ * D_ * 2);
    u16* Wo    = (u16*)alloc((size_t)D_ * D_ * 2);
    float* QK  = (float*)alloc((size_t)T_ * B_ * D_ * 4);
    u8* QKs    = (u8*)alloc((size_t)T_ * B_ * D_);
    int* rowlist = (int*)alloc((size_t)3 * BS_ * 4);
    int* cnt   = (int*)alloc(256);

    hipMemsetAsync(QK, 0, (size_t)T_ * B_ * D_ * 4, stream);
    hipMemsetAsync(cnt, 0, 12, stream);

    // 1. IF over x -> bitmasks + bf16 spikes (bit-exact)
    k_if_mask<<<BS_, 768, 0, stream>>>(x, Am, Ab);
    // 2. weight conversion
    k_wconv<<<(4 * D_ * D_) / 256, 256, 0, stream>>>(wq, wk, wv, wo, Whi, Wlo, Wo);
    // 3. Q/K/V: split-bf16 MFMA GEMM (single pass, hi+lo) + f64-LN + IF + row flags
    const int ntn = D_ / 128;                           // 6
    const int gemm_grid = (M_ / 128) * ntn;             // 1536 (%8==0 for XCD swizzle)
    k_gemm<2><<<gemm_grid, 256, 0, stream>>>(Ab, Whi + 0 * D_ * D_, Wlo + 0 * D_ * D_, Y, ntn, D_);
    k_lnif<<<BS_ / 4, 256, 0, stream>>>(Y, gq, bq, Qs, rowlist, cnt, 0);
    k_gemm<2><<<gemm_grid, 256, 0, stream>>>(Ab, Whi + 1 * D_ * D_, Wlo + 1 * D_ * D_, Y, ntn, D_);
    k_lnif<<<BS_ / 4, 256, 0, stream>>>(Y, gk, bk, Ks, rowlist, cnt, 1);
    k_gemm<2><<<gemm_grid, 256, 0, stream>>>(Ab, Whi + 2 * D_ * D_, Wlo + 2 * D_ * D_, Y, ntn, D_);
    k_lnif<<<BS_ / 4, 256, 0, stream>>>(Y, gv, bv, Vs, rowlist, cnt, 2);
    // 3b. exact row repair (union walk, 2 rows/block; np arithmetic preserved)
    k_repairU<<<dim3(BS_ / 2, 3), 192, 0, stream>>>(Am, wq, wk, wv, gq, bq, gk, bk, gv, bv,
                                                    Qs, Ks, Vs, rowlist, cnt);
    // 4. QK column-dot + IF (integer-exact)
    k_qkred<<<T_ * B_ * 32, 192, 0, stream>>>(Qs, Ks, QK);
    k_qkif<<<(B_ * D_) / 256, 256, 0, stream>>>(QK, QKs);
    // 5. QKV = V * QKs -> bf16 (reuse Ab)
    k_qkv<<<(M_ * D_) / 4 / 256, 256, 0, stream>>>(Vs, QKs, Ab);
    // 6. output projection (bf16 MFMA; loose tolerance) + final LN
    k_gemm<1><<<gemm_grid, 256, 0, stream>>>(Ab, Wo, Wo, Y, ntn, D_);
    k_lnfinal<<<M_, 256, 0, stream>>>(Y, go, bo, out);
}

// Round 9
// 593.831 us; speedup vs baseline: 1.1673x; 1.1673x over previous
//
#include <hip/hip_runtime.h>
#include <hip/hip_bf16.h>

#define T_ 4
#define B_ 8
#define S_ 1024
#define D_ 768
#define BS_ (B_*S_)            // 8192
#define M_ (T_*B_*S_)          // 32768
#define BSD_ (B_*S_*D_)        // 6291456
#define LN_EPS 1e-5f
#define TAU 4e-5f

typedef unsigned short u16;
typedef unsigned char u8;
typedef unsigned int u32;
typedef unsigned long long u64;
typedef __bf16 bf16x8 __attribute__((ext_vector_type(8)));
typedef float f32x4 __attribute__((ext_vector_type(4)));

// ---- IF over x -> bitmask spikes + bf16 spikes, bit-exact vs np ----
__global__ __launch_bounds__(768)
void k_if_mask(const float* __restrict__ x, u64* __restrict__ Am, u16* __restrict__ Ab) {
    int bs = blockIdx.x;           // 8192 blocks
    int d = threadIdx.x;           // 768 threads
    int wv = d >> 6, lane = d & 63;
    float v = 0.f;
    for (int t = 0; t < T_; ++t) {
        v += x[(size_t)t * BSD_ + (size_t)bs * D_ + d];
        bool s = (v >= 1.0f);
        u64 m = __ballot(s);
        if (lane == 0) Am[((size_t)t * 12 + wv) * BS_ + bs] = m;
        Ab[(size_t)t * BSD_ + (size_t)bs * D_ + d] = s ? 0x3F80 : 0;
        if (s) v = 0.f;
    }
}

// ---- weight convert: Bt layout [N][K], hi/lo split for q/k/v; bf16 for wo ----
__global__ void k_wconv(const float* __restrict__ wq, const float* __restrict__ wk,
                        const float* __restrict__ wv, const float* __restrict__ wo,
                        u16* __restrict__ Whi, u16* __restrict__ Wlo, u16* __restrict__ Wo) {
    int idx = blockIdx.x * 256 + threadIdx.x;       // 9216 blocks
    int mat = idx / (D_ * D_);
    int r = idx % (D_ * D_);
    int n = r / D_;
    int k = r % D_;
    const float* src = (mat == 0) ? wq : (mat == 1) ? wk : (mat == 2) ? wv : wo;
    float w = src[k * D_ + n];
    __bf16 hi = (__bf16)w;
    u16 uhi = __builtin_bit_cast(u16, hi);
    if (mat == 3) { Wo[r] = uhi; return; }
    float lo = w - (float)hi;
    u16 ulo = __builtin_bit_cast(u16, (__bf16)lo);
    Whi[(size_t)mat * D_ * D_ + r] = uhi;
    Wlo[(size_t)mat * D_ * D_ + r] = ulo;
}

// ---- MFMA GEMM: C = A @ Bhi^T (+ A @ Blo^T if NMATS==2), single K pass ----
__device__ __forceinline__ void gload16(const void* g, void* l) {
    __builtin_amdgcn_global_load_lds(
        (const __attribute__((address_space(1))) unsigned int*)g,
        (__attribute__((address_space(3))) unsigned int*)l, 16, 0, 0);
}

template<int NMATS>
__global__ __launch_bounds__(256)
void k_gemm(const u16* __restrict__ A, const u16* __restrict__ Bhi,
            const u16* __restrict__ Blo, float* __restrict__ C, int ntn, int N) {
    __shared__ __align__(16) u16 As[128 * 32];
    __shared__ __align__(16) u16 Bh[128 * 32];
    __shared__ __align__(16) u16 Bl[128 * 32];
    int bid = blockIdx.x;
    bid = (bid & 7) * (gridDim.x >> 3) + (bid >> 3);   // XCD chunked swizzle (grid%8==0)
    int bn = bid % ntn, bm = bid / ntn;
    int tid = threadIdx.x;
    int l = tid & 63, w = tid >> 6;
    int wr = w >> 1, wc = w & 1;
    int lan16 = l & 15, kh = l >> 4;

    f32x4 acc[4][4];
    #pragma unroll
    for (int m = 0; m < 4; ++m)
        #pragma unroll
        for (int n = 0; n < 4; ++n)
            #pragma unroll
            for (int r = 0; r < 4; ++r) acc[m][n][r] = 0.f;

    int arow = bm * 128 + (tid >> 2);
    int brow = bn * 128 + (tid >> 2);
    int colb = (((tid & 3) ^ ((tid >> 3) & 3)) * 8);   // pre-swizzled source chunk
    char* ldsA = (char*)As + ((tid >> 6) << 10);
    char* ldsBh = (char*)Bh + ((tid >> 6) << 10);
    char* ldsBl = (char*)Bl + ((tid >> 6) << 10);

    int khs16 = (kh ^ ((lan16 >> 1) & 3)) << 4;        // swizzled read chunk byte
    int aoff[4], boff[4];
    #pragma unroll
    for (int m = 0; m < 4; ++m) aoff[m] = (wr * 64 + m * 16 + lan16) * 64 + khs16;
    #pragma unroll
    for (int n = 0; n < 4; ++n) boff[n] = (wc * 64 + n * 16 + lan16) * 64 + khs16;

    for (int kk = 0; kk < 768; kk += 32) {
        gload16(A   + (size_t)(arow     ) * 768 + kk + colb, ldsA);
        gload16(A   + (size_t)(arow + 64) * 768 + kk + colb, ldsA + 4096);
        gload16(Bhi + (size_t)(brow     ) * 768 + kk + colb, ldsBh);
        gload16(Bhi + (size_t)(brow + 64) * 768 + kk + colb, ldsBh + 4096);
        if (NMATS == 2) {
            gload16(Blo + (size_t)(brow     ) * 768 + kk + colb, ldsBl);
            gload16(Blo + (size_t)(brow + 64) * 768 + kk + colb, ldsBl + 4096);
        }
        __syncthreads();
        bf16x8 af[4], bh[4], bl[4];
        #pragma unroll
        for (int m = 0; m < 4; ++m)
            af[m] = *(const bf16x8*)((const char*)As + aoff[m]);
        #pragma unroll
        for (int n = 0; n < 4; ++n) {
            bh[n] = *(const bf16x8*)((const char*)Bh + boff[n]);
            if (NMATS == 2) bl[n] = *(const bf16x8*)((const char*)Bl + boff[n]);
        }
        #pragma unroll
        for (int m = 0; m < 4; ++m)
            #pragma unroll
            for (int n = 0; n < 4; ++n) {
                acc[m][n] = __builtin_amdgcn_mfma_f32_16x16x32_bf16(af[m], bh[n], acc[m][n], 0, 0, 0);
                if (NMATS == 2)
                    acc[m][n] = __builtin_amdgcn_mfma_f32_16x16x32_bf16(af[m], bl[n], acc[m][n], 0, 0, 0);
            }
        __syncthreads();
    }
    #pragma unroll
    for (int m = 0; m < 4; ++m)
        #pragma unroll
        for (int n = 0; n < 4; ++n)
            #pragma unroll
            for (int r = 0; r < 4; ++r) {
                int crow = bm * 128 + wr * 64 + m * 16 + kh * 4 + r;
                int ccol = bn * 128 + wc * 64 + n * 16 + lan16;
                C[(size_t)crow * N + ccol] = acc[m][n][r];
            }
}

// ---- LN (f64 mean/var) + IF -> u8 spikes; flagged rows -> compact list ----
__global__ __launch_bounds__(256)
void k_lnif(const float* __restrict__ Y, const float* __restrict__ g,
            const float* __restrict__ bt, u8* __restrict__ Sp,
            int* __restrict__ rowlist, int* __restrict__ cnt, int mat) {
    #pragma clang fp contract(off)
    int row = blockIdx.x * 4 + (threadIdx.x >> 6);   // (b,s) 0..8191
    int lane = threadIdx.x & 63;
    float v[12];
    #pragma unroll
    for (int i = 0; i < 12; ++i) v[i] = 0.f;
    float gv[12], bv[12];
    #pragma unroll
    for (int i = 0; i < 12; ++i) { gv[i] = g[lane + 64*i]; bv[i] = bt[lane + 64*i]; }
    bool fl = false;
    for (int t = 0; t < T_; ++t) {
        size_t base = ((size_t)t * BS_ + row) * D_;
        float xv[12];
        double s = 0.0;
        #pragma unroll
        for (int i = 0; i < 12; ++i) { xv[i] = Y[base + lane + 64*i]; s += (double)xv[i]; }
        #pragma unroll
        for (int o = 1; o < 64; o <<= 1) s += __shfl_xor(s, o, 64);
        s = __shfl(s, 0, 64);
        float m = (float)(s / 768.0);
        float d[12];
        double q = 0.0;
        #pragma unroll
        for (int i = 0; i < 12; ++i) { d[i] = xv[i] - m; float sq = d[i]*d[i]; q += (double)sq; }
        #pragma unroll
        for (int o = 1; o < 64; o <<= 1) q += __shfl_xor(q, o, 64);
        q = __shfl(q, 0, 64);
        float var = (float)(q / 768.0);
        float inv = 1.0f / __fsqrt_rn(var + LN_EPS);
        #pragma unroll
        for (int i = 0; i < 12; ++i) {
            float yn = ((d[i] * inv) * gv[i]) + bv[i];
            v[i] += yn;
            fl = fl || (fabsf(v[i] - 1.0f) < TAU);
            bool sp = (v[i] >= 1.0f);
            Sp[base + lane + 64*i] = sp ? (u8)1 : (u8)0;
            if (sp) v[i] = 0.f;
        }
    }
    u64 bal = __ballot(fl);
    if (lane == 0 && bal != 0ull) {
        int slot = atomicAdd(cnt + mat, 1);
        rowlist[mat * BS_ + slot] = row;
    }
}

// ---- row repair: per-(row,t) branchless dense walks, t parallel across waves ----
// 768 threads = 4 t-subgroups x 192 col-groups. Each thread walks its t's
// dense ascending-k index list (exact np sgemm rounding order), then the t=0
// subgroup combines y(t) via LDS for the f32 IF chain with f64 LN stats.
__global__ __launch_bounds__(768)
void k_repairT(const u64* __restrict__ Am,
               const float* __restrict__ wq, const float* __restrict__ wk,
               const float* __restrict__ wv,
               const float* __restrict__ gq, const float* __restrict__ bq,
               const float* __restrict__ gk, const float* __restrict__ bk,
               const float* __restrict__ gv, const float* __restrict__ bv,
               u8* __restrict__ Qs, u8* __restrict__ Ks, u8* __restrict__ Vs,
               const int* __restrict__ rowlist, const int* __restrict__ cnt) {
    #pragma clang fp contract(off)
    int mat = blockIdx.y;
    if (blockIdx.x >= cnt[mat]) return;
    int row = rowlist[mat * BS_ + blockIdx.x];
    const float* W = (mat == 0) ? wq : (mat == 1) ? wk : wv;
    const float* g = (mat == 0) ? gq : (mat == 1) ? gk : gv;
    const float* bb = (mat == 0) ? bq : (mat == 1) ? bk : bv;
    u8* Sp = (mat == 0) ? Qs : (mat == 1) ? Ks : Vs;
    const float4* Wv4 = (const float4*)W;

    __shared__ u64 mks[4][12];
    __shared__ int pops[4][12];
    __shared__ int cnt4[4];
    __shared__ u16 idxs[4][768];
    __shared__ float4 ys[4][192];
    __shared__ float2 mi_sh[4];
    __shared__ double redd[12];

    int tid = threadIdx.x;
    int t = tid / 192;                 // 0..3 (3 waves per t-subgroup)
    int tg = tid % 192;                // col-group: cols 4tg..4tg+3

    if (tid < 48) {
        int tt = tid / 12, kw = tid % 12;
        u64 m = Am[((size_t)tt * 12 + kw) * BS_ + row];
        mks[tt][kw] = m;
        pops[tt][kw] = __popcll(m);
    }
    __syncthreads();
    if (tid < 48) {
        int tt = tid / 12, kw = tid % 12;
        int off = 0;
        for (int j = 0; j < kw; ++j) off += pops[tt][j];
        u64 m = mks[tt][kw];
        int kb0 = kw * 64;
        while (m) {
            int kb = __builtin_ctzll(m);
            m &= m - 1;
            idxs[tt][off++] = (u16)(kb0 + kb);
        }
        if (kw == 11) cnt4[tt] = off;
    }
    __syncthreads();

    // branchless dense walk: exact ascending-k sequential f32 adds (np order)
    int cn = cnt4[t];
    float y0 = 0.f, y1 = 0.f, y2 = 0.f, y3 = 0.f;
    const u16* il = idxs[t];
    #pragma unroll 8
    for (int i = 0; i < cn; ++i) {
        float4 w = Wv4[(size_t)il[i] * 192 + tg];
        y0 += w.x; y1 += w.y; y2 += w.z; y3 += w.w;
    }

    // f64 LN stats per t over this t-subgroup's 192 threads (3 waves)
    int lane = tid & 63;
    int wv_t = tg >> 6;                // wave index within t-subgroup (0..2)
    double s = (double)y0 + (double)y1 + (double)y2 + (double)y3;
    #pragma unroll
    for (int o = 1; o < 64; o <<= 1) s += __shfl_xor(s, o, 64);
    if (lane == 0) redd[t * 3 + wv_t] = s;
    __syncthreads();
    double stot = redd[t * 3] + redd[t * 3 + 1] + redd[t * 3 + 2];
    float mean = (float)(stot / 768.0);
    float d0 = y0 - mean, d1 = y1 - mean, d2 = y2 - mean, d3 = y3 - mean;
    double q = (double)(d0*d0) + (double)(d1*d1) + (double)(d2*d2) + (double)(d3*d3);
    #pragma unroll
    for (int o = 1; o < 64; o <<= 1) q += __shfl_xor(q, o, 64);
    __syncthreads();
    if (lane == 0) redd[t * 3 + wv_t] = q;
    __syncthreads();
    double qtot = redd[t * 3] + redd[t * 3 + 1] + redd[t * 3 + 2];
    float var = (float)(qtot / 768.0);
    float inv = 1.0f / __fsqrt_rn(var + LN_EPS);

    ys[t][tg] = make_float4(y0, y1, y2, y3);
    if (tg == 0) mi_sh[t] = make_float2(mean, inv);
    __syncthreads();

    // IF chain (t ascending) on the t=0 subgroup; writes all 4 t spike rows
    if (tid < 192) {
        float4 gd = ((const float4*)g)[tg];
        float4 bd = ((const float4*)bb)[tg];
        float4 yt[4];
        float2 mi[4];
        #pragma unroll
        for (int tt = 0; tt < 4; ++tt) { yt[tt] = ys[tt][tg]; mi[tt] = mi_sh[tt]; }
        uchar4 o4[4];
        #pragma unroll
        for (int j = 0; j < 4; ++j) {
            float gj = (j == 0) ? gd.x : (j == 1) ? gd.y : (j == 2) ? gd.z : gd.w;
            float bj = (j == 0) ? bd.x : (j == 1) ? bd.y : (j == 2) ? bd.z : bd.w;
            float v = 0.f;
            #pragma unroll
            for (int tt = 0; tt < 4; ++tt) {
                float yj = (j == 0) ? yt[tt].x : (j == 1) ? yt[tt].y : (j == 2) ? yt[tt].z : yt[tt].w;
                float d = yj - mi[tt].x;
                float yn = ((d * mi[tt].y) * gj) + bj;
                v += yn;
                bool sp = (v >= 1.0f);
                u8 sb = sp ? (u8)1 : (u8)0;
                if (j == 0) o4[tt].x = sb;
                if (j == 1) o4[tt].y = sb;
                if (j == 2) o4[tt].z = sb;
                if (j == 3) o4[tt].w = sb;
                if (sp) v = 0.f;
            }
        }
        #pragma unroll
        for (int tt = 0; tt < 4; ++tt)
            *(uchar4*)(Sp + ((size_t)tt * BS_ + row) * D_ + tg * 4) = o4[tt];
    }
}

// ---- QK column-dot over S (exact integer counts) ----
__global__ void k_qkred(const u8* __restrict__ Q, const u8* __restrict__ K,
                        float* __restrict__ QK) {
    int bid = blockIdx.x;           // 1024 blocks, 192 threads
    int sg = bid & 31, tb = bid >> 5;
    int tid = threadIdx.x;
    int c4 = tid * 4;
    size_t base = (size_t)tb * S_ * D_ + (size_t)sg * 32 * D_;
    int acc[4] = {0, 0, 0, 0};
    for (int s = 0; s < 32; ++s) {
        uchar4 q = *(const uchar4*)(Q + base + (size_t)s * D_ + c4);
        uchar4 k = *(const uchar4*)(K + base + (size_t)s * D_ + c4);
        acc[0] += q.x & k.x; acc[1] += q.y & k.y; acc[2] += q.z & k.z; acc[3] += q.w & k.w;
    }
    float* dst = QK + (size_t)tb * D_ + c4;
    #pragma unroll
    for (int j = 0; j < 4; ++j) atomicAdd(dst + j, (float)acc[j]);
}

// ---- IF over T on QK counts (integer-exact) ----
__global__ void k_qkif(const float* __restrict__ QK, u8* __restrict__ QKs) {
    int i = blockIdx.x * 256 + threadIdx.x;     // 24 blocks
    float v = 0.f;
    for (int t = 0; t < T_; ++t) {
        v += QK[t * (B_ * D_) + i];
        bool s = (v >= 1.0f);
        QKs[t * (B_ * D_) + i] = s ? 1 : 0;
        if (s) v = 0.f;
    }
}

// ---- QKV = V * QKs -> bf16 {0,1} ----
__global__ void k_qkv(const u8* __restrict__ V, const u8* __restrict__ QKs,
                      u16* __restrict__ O) {
    size_t e = ((size_t)blockIdx.x * 256 + threadIdx.x) * 4;    // 24576 blocks
    uchar4 v = *(const uchar4*)(V + e);
    size_t d = e % D_;
    size_t b = (e / ((size_t)S_ * D_)) % B_;
    size_t t = e / BSD_;
    uchar4 qk = *(const uchar4*)(QKs + t * (B_ * D_) + b * D_ + d);
    ushort4 o;
    o.x = (v.x & qk.x) ? 0x3F80 : 0;
    o.y = (v.y & qk.y) ? 0x3F80 : 0;
    o.z = (v.z & qk.z) ? 0x3F80 : 0;
    o.w = (v.w & qk.w) ? 0x3F80 : 0;
    *(ushort4*)(O + e) = o;
}

// ---- block reduction helper (final LN only; tolerance loose) ----
__device__ __forceinline__ float block_sum(float v, float* red) {
    #pragma unroll
    for (int o = 32; o > 0; o >>= 1) v += __shfl_down(v, o, 64);
    int lane = threadIdx.x & 63, w = threadIdx.x >> 6;
    __syncthreads();
    if (lane == 0) red[w] = v;
    __syncthreads();
    return (red[0] + red[1]) + (red[2] + red[3]);
}

__global__ __launch_bounds__(256)
void k_lnfinal(const float* __restrict__ Y, const float* __restrict__ g,
               const float* __restrict__ bt, float* __restrict__ out) {
    #pragma clang fp contract(off)
    __shared__ float red[4];
    size_t row = (size_t)blockIdx.x * D_;       // 32768 rows
    int tid = threadIdx.x;
    float y[3];
    float s = 0.f;
    #pragma unroll
    for (int j = 0; j < 3; ++j) { y[j] = Y[row + tid + j * 256]; s += y[j]; }
    float mean = block_sum(s, red) / 768.0f;
    float q = 0.f;
    #pragma unroll
    for (int j = 0; j < 3; ++j) { float d = y[j] - mean; q += d * d; }
    float var = block_sum(q, red) / 768.0f;
    float inv = 1.0f / __fsqrt_rn(var + LN_EPS);
    #pragma unroll
    for (int j = 0; j < 3; ++j) {
        int c = tid + j * 256;
        out[row + c] = (y[j] - mean) * inv * g[c] + bt[c];
    }
}

extern "C" void kernel_launch(void* const* d_in, const int* in_sizes, int n_in,
                              void* d_out, int out_size, void* d_ws, size_t ws_size,
                              hipStream_t stream) {
    const float* x  = (const float*)d_in[0];
    const float* wq = (const float*)d_in[1];
    const float* wk = (const float*)d_in[2];
    const float* wv = (const float*)d_in[3];
    const float* wo = (const float*)d_in[4];
    const float* gq = (const float*)d_in[5];
    const float* bq = (const float*)d_in[6];
    const float* gk = (const float*)d_in[7];
    const float* bk = (const float*)d_in[8];
    const float* gv = (const float*)d_in[9];
    const float* bv = (const float*)d_in[10];
    const float* go = (const float*)d_in[11];
    const float* bo = (const float*)d_in[12];
    float* out = (float*)d_out;

    char* ws = (char*)d_ws;
    size_t off = 0;
    auto alloc = [&](size_t bytes) -> void* {
        void* p = ws + off;
        off += (bytes + 255) & ~(size_t)255;
        return p;
    };
    u64* Am    = (u64*)alloc((size_t)T_ * 12 * BS_ * 8);     // 3 MB bitmasks
    u16* Ab    = (u16*)alloc((size_t)M_ * D_ * 2);           // 48 MB bf16 spikes / reused for QKV
    float* Y   = (float*)alloc((size_t)M_ * D_ * 4);         // 96 MB GEMM out
    u8* Qs     = (u8*)alloc((size_t)M_ * D_);
    u8* Ks     = (u8*)alloc((size_t)M_ * D_);
    u8* Vs     = (u8*)alloc((size_t)M_ * D_);
    u16* Whi   = (u16*)alloc((size_t)3 * D_ * D_ * 2);
    u16* Wlo   = (u16*)alloc((size_t)3 * D_ * D_ * 2);
    u16* Wo    = (u16*)alloc((size_t)D_ * D_ * 2);
    float* QK  = (float*)alloc((size_t)T_ * B_ * D_ * 4);
    u8* QKs    = (u8*)alloc((size_t)T_ * B_ * D_);
    int* rowlist = (int*)alloc((size_t)3 * BS_ * 4);
    int* cnt   = (int*)alloc(256);

    hipMemsetAsync(QK, 0, (size_t)T_ * B_ * D_ * 4, stream);
    hipMemsetAsync(cnt, 0, 12, stream);

    // 1. IF over x -> bitmasks + bf16 spikes (bit-exact)
    k_if_mask<<<BS_, 768, 0, stream>>>(x, Am, Ab);
    // 2. weight conversion
    k_wconv<<<(4 * D_ * D_) / 256, 256, 0, stream>>>(wq, wk, wv, wo, Whi, Wlo, Wo);
    // 3. Q/K/V: split-bf16 MFMA GEMM (single pass, hi+lo) + f64-LN + IF + row flags
    const int ntn = D_ / 128;                           // 6
    const int gemm_grid = (M_ / 128) * ntn;             // 1536 (%8==0 for XCD swizzle)
    k_gemm<2><<<gemm_grid, 256, 0, stream>>>(Ab, Whi + 0 * D_ * D_, Wlo + 0 * D_ * D_, Y, ntn, D_);
    k_lnif<<<BS_ / 4, 256, 0, stream>>>(Y, gq, bq, Qs, rowlist, cnt, 0);
    k_gemm<2><<<gemm_grid, 256, 0, stream>>>(Ab, Whi + 1 * D_ * D_, Wlo + 1 * D_ * D_, Y, ntn, D_);
    k_lnif<<<BS_ / 4, 256, 0, stream>>>(Y, gk, bk, Ks, rowlist, cnt, 1);
    k_gemm<2><<<gemm_grid, 256, 0, stream>>>(Ab, Whi + 2 * D_ * D_, Wlo + 2 * D_ * D_, Y, ntn, D_);
    k_lnif<<<BS_ / 4, 256, 0, stream>>>(Y, gv, bv, Vs, rowlist, cnt, 2);
    // 3b. exact row repair (branchless per-(row,t) walks, t parallel)
    k_repairT<<<dim3(BS_, 3), 768, 0, stream>>>(Am, wq, wk, wv, gq, bq, gk, bk, gv, bv,
                                                Qs, Ks, Vs, rowlist, cnt);
    // 4. QK column-dot + IF (integer-exact)
    k_qkred<<<T_ * B_ * 32, 192, 0, stream>>>(Qs, Ks, QK);
    k_qkif<<<(B_ * D_) / 256, 256, 0, stream>>>(QK, QKs);
    // 5. QKV = V * QKs -> bf16 (reuse Ab)
    k_qkv<<<(M_ * D_) / 4 / 256, 256, 0, stream>>>(Vs, QKs, Ab);
    // 6. output projection (bf16 MFMA; loose tolerance) + final LN
    k_gemm<1><<<gemm_grid, 256, 0, stream>>>(Ab, Wo, Wo, Y, ntn, D_);
    k_lnfinal<<<M_, 256, 0, stream>>>(Y, go, bo, out);
}

// Round 10
// 552.174 us; speedup vs baseline: 1.2554x; 1.0754x over previous
//
#include <hip/hip_runtime.h>
#include <hip/hip_bf16.h>

#define T_ 4
#define B_ 8
#define S_ 1024
#define D_ 768
#define BS_ (B_*S_)            // 8192
#define M_ (T_*B_*S_)          // 32768
#define BSD_ (B_*S_*D_)        // 6291456
#define LN_EPS 1e-5f
#define TAU 4e-5f

typedef unsigned short u16;
typedef unsigned char u8;
typedef unsigned int u32;
typedef unsigned long long u64;
typedef __bf16 bf16x8 __attribute__((ext_vector_type(8)));
typedef float f32x4 __attribute__((ext_vector_type(4)));

// ---- IF over x -> bitmask spikes + bf16 spikes, bit-exact vs np ----
__global__ __launch_bounds__(768)
void k_if_mask(const float* __restrict__ x, u64* __restrict__ Am, u16* __restrict__ Ab) {
    int bs = blockIdx.x;           // 8192 blocks
    int d = threadIdx.x;           // 768 threads
    int wv = d >> 6, lane = d & 63;
    float v = 0.f;
    for (int t = 0; t < T_; ++t) {
        v += x[(size_t)t * BSD_ + (size_t)bs * D_ + d];
        bool s = (v >= 1.0f);
        u64 m = __ballot(s);
        if (lane == 0) Am[((size_t)t * 12 + wv) * BS_ + bs] = m;
        Ab[(size_t)t * BSD_ + (size_t)bs * D_ + d] = s ? 0x3F80 : 0;
        if (s) v = 0.f;
    }
}

// ---- weight convert: Bt layout [N][K], hi/lo split for q/k/v; bf16 for wo ----
__global__ void k_wconv(const float* __restrict__ wq, const float* __restrict__ wk,
                        const float* __restrict__ wv, const float* __restrict__ wo,
                        u16* __restrict__ Whi, u16* __restrict__ Wlo, u16* __restrict__ Wo) {
    int idx = blockIdx.x * 256 + threadIdx.x;       // 9216 blocks
    int mat = idx / (D_ * D_);
    int r = idx % (D_ * D_);
    int n = r / D_;
    int k = r % D_;
    const float* src = (mat == 0) ? wq : (mat == 1) ? wk : (mat == 2) ? wv : wo;
    float w = src[k * D_ + n];
    __bf16 hi = (__bf16)w;
    u16 uhi = __builtin_bit_cast(u16, hi);
    if (mat == 3) { Wo[r] = uhi; return; }
    float lo = w - (float)hi;
    u16 ulo = __builtin_bit_cast(u16, (__bf16)lo);
    Whi[(size_t)mat * D_ * D_ + r] = uhi;
    Wlo[(size_t)mat * D_ * D_ + r] = ulo;
}

// ---- MFMA GEMM: C = A @ Bhi^T (+ A @ Blo^T if NMATS==2), BK=64 ----
// LDS tile [128 rows][8 chunks of 16B], physical chunk p = c ^ (row&7).
// Staging keeps LDS linear (gload_lds constraint) and pre-swizzles the
// GLOBAL source chunk; reads XOR the chunk index. Quarter-wave ds_read_b128
// spans all 8 bank groups at 2-way aliasing (free).
__device__ __forceinline__ void gload16(const void* g, void* l) {
    __builtin_amdgcn_global_load_lds(
        (const __attribute__((address_space(1))) unsigned int*)g,
        (__attribute__((address_space(3))) unsigned int*)l, 16, 0, 0);
}

template<int NMATS>
__global__ __launch_bounds__(256)
void k_gemm(const u16* __restrict__ A, const u16* __restrict__ Bhi,
            const u16* __restrict__ Blo, float* __restrict__ C, int ntn, int N) {
    __shared__ __align__(16) u16 As[128 * 64];
    __shared__ __align__(16) u16 Bh[128 * 64];
    __shared__ __align__(16) u16 Bl[NMATS == 2 ? 128 * 64 : 8];
    int bid = blockIdx.x;
    bid = (bid & 7) * (gridDim.x >> 3) + (bid >> 3);   // XCD chunked swizzle (grid%8==0)
    int bn = bid % ntn, bm = bid / ntn;
    int tid = threadIdx.x;
    int l = tid & 63, w = tid >> 6;
    int wr = w >> 1, wc = w & 1;
    int lan16 = l & 15, kh = l >> 4;

    f32x4 acc[4][4];
    #pragma unroll
    for (int m = 0; m < 4; ++m)
        #pragma unroll
        for (int n = 0; n < 4; ++n)
            #pragma unroll
            for (int r = 0; r < 4; ++r) acc[m][n][r] = 0.f;

    // staging: 4 chunk-loads per matrix per K-step; li = j*256+tid
    // row = li>>3 in [0,128), source chunk c = (li&7) ^ (row&7)  (pre-swizzle)
    int srow[4], scol[4];
    #pragma unroll
    for (int j = 0; j < 4; ++j) {
        int li = j * 256 + tid;
        srow[j] = li >> 3;
        scol[j] = ((li & 7) ^ ((li >> 3) & 7)) * 8;
    }
    int wbase = (tid >> 6) << 10;     // wave-uniform LDS byte base within 4KB group

    // read offsets [frag][substep]: row R, chunk (s*4+kh) ^ (R&7); R&7 == lan16&7
    int aoff[4][2], boff[4][2];
    #pragma unroll
    for (int m = 0; m < 4; ++m)
        #pragma unroll
        for (int s = 0; s < 2; ++s) {
            int Ra = wr * 64 + m * 16 + lan16;
            aoff[m][s] = Ra * 128 + (((s * 4 + kh) ^ (Ra & 7)) << 4);
            int Rb = wc * 64 + m * 16 + lan16;
            boff[m][s] = Rb * 128 + (((s * 4 + kh) ^ (Rb & 7)) << 4);
        }

    for (int kk = 0; kk < 768; kk += 64) {
        #pragma unroll
        for (int j = 0; j < 4; ++j) {
            gload16(A   + (size_t)(bm * 128 + srow[j]) * 768 + kk + scol[j],
                    (char*)As + j * 4096 + wbase);
            gload16(Bhi + (size_t)(bn * 128 + srow[j]) * 768 + kk + scol[j],
                    (char*)Bh + j * 4096 + wbase);
            if (NMATS == 2)
                gload16(Blo + (size_t)(bn * 128 + srow[j]) * 768 + kk + scol[j],
                        (char*)Bl + j * 4096 + wbase);
        }
        __syncthreads();
        #pragma unroll
        for (int s = 0; s < 2; ++s) {
            bf16x8 af[4], bh[4], bl[4];
            #pragma unroll
            for (int m = 0; m < 4; ++m)
                af[m] = *(const bf16x8*)((const char*)As + aoff[m][s]);
            #pragma unroll
            for (int n = 0; n < 4; ++n) {
                bh[n] = *(const bf16x8*)((const char*)Bh + boff[n][s]);
                if (NMATS == 2) bl[n] = *(const bf16x8*)((const char*)Bl + boff[n][s]);
            }
            #pragma unroll
            for (int m = 0; m < 4; ++m)
                #pragma unroll
                for (int n = 0; n < 4; ++n) {
                    acc[m][n] = __builtin_amdgcn_mfma_f32_16x16x32_bf16(af[m], bh[n], acc[m][n], 0, 0, 0);
                    if (NMATS == 2)
                        acc[m][n] = __builtin_amdgcn_mfma_f32_16x16x32_bf16(af[m], bl[n], acc[m][n], 0, 0, 0);
                }
        }
        __syncthreads();
    }
    #pragma unroll
    for (int m = 0; m < 4; ++m)
        #pragma unroll
        for (int n = 0; n < 4; ++n)
            #pragma unroll
            for (int r = 0; r < 4; ++r) {
                int crow = bm * 128 + wr * 64 + m * 16 + kh * 4 + r;
                int ccol = bn * 128 + wc * 64 + n * 16 + lan16;
                C[(size_t)crow * N + ccol] = acc[m][n][r];
            }
}

// ---- LN (f64 mean/var) + IF -> u8 spikes; flagged rows -> compact list ----
__global__ __launch_bounds__(256)
void k_lnif(const float* __restrict__ Y, const float* __restrict__ g,
            const float* __restrict__ bt, u8* __restrict__ Sp,
            int* __restrict__ rowlist, int* __restrict__ cnt, int mat) {
    #pragma clang fp contract(off)
    int row = blockIdx.x * 4 + (threadIdx.x >> 6);   // (b,s) 0..8191
    int lane = threadIdx.x & 63;
    float v[12];
    #pragma unroll
    for (int i = 0; i < 12; ++i) v[i] = 0.f;
    float gv[12], bv[12];
    #pragma unroll
    for (int i = 0; i < 12; ++i) { gv[i] = g[lane + 64*i]; bv[i] = bt[lane + 64*i]; }
    bool fl = false;
    for (int t = 0; t < T_; ++t) {
        size_t base = ((size_t)t * BS_ + row) * D_;
        float xv[12];
        double s = 0.0;
        #pragma unroll
        for (int i = 0; i < 12; ++i) { xv[i] = Y[base + lane + 64*i]; s += (double)xv[i]; }
        #pragma unroll
        for (int o = 1; o < 64; o <<= 1) s += __shfl_xor(s, o, 64);
        s = __shfl(s, 0, 64);
        float m = (float)(s / 768.0);
        float d[12];
        double q = 0.0;
        #pragma unroll
        for (int i = 0; i < 12; ++i) { d[i] = xv[i] - m; float sq = d[i]*d[i]; q += (double)sq; }
        #pragma unroll
        for (int o = 1; o < 64; o <<= 1) q += __shfl_xor(q, o, 64);
        q = __shfl(q, 0, 64);
        float var = (float)(q / 768.0);
        float inv = 1.0f / __fsqrt_rn(var + LN_EPS);
        #pragma unroll
        for (int i = 0; i < 12; ++i) {
            float yn = ((d[i] * inv) * gv[i]) + bv[i];
            v[i] += yn;
            fl = fl || (fabsf(v[i] - 1.0f) < TAU);
            bool sp = (v[i] >= 1.0f);
            Sp[base + lane + 64*i] = sp ? (u8)1 : (u8)0;
            if (sp) v[i] = 0.f;
        }
    }
    u64 bal = __ballot(fl);
    if (lane == 0 && bal != 0ull) {
        int slot = atomicAdd(cnt + mat, 1);
        rowlist[mat * BS_ + slot] = row;
    }
}

// ---- row repair: per-(row,t) branchless dense walks, t parallel across waves ----
__global__ __launch_bounds__(768)
void k_repairT(const u64* __restrict__ Am,
               const float* __restrict__ wq, const float* __restrict__ wk,
               const float* __restrict__ wv,
               const float* __restrict__ gq, const float* __restrict__ bq,
               const float* __restrict__ gk, const float* __restrict__ bk,
               const float* __restrict__ gv, const float* __restrict__ bv,
               u8* __restrict__ Qs, u8* __restrict__ Ks, u8* __restrict__ Vs,
               const int* __restrict__ rowlist, const int* __restrict__ cnt) {
    #pragma clang fp contract(off)
    int mat = blockIdx.y;
    if (blockIdx.x >= cnt[mat]) return;
    int row = rowlist[mat * BS_ + blockIdx.x];
    const float* W = (mat == 0) ? wq : (mat == 1) ? wk : wv;
    const float* g = (mat == 0) ? gq : (mat == 1) ? gk : gv;
    const float* bb = (mat == 0) ? bq : (mat == 1) ? bk : bv;
    u8* Sp = (mat == 0) ? Qs : (mat == 1) ? Ks : Vs;
    const float4* Wv4 = (const float4*)W;

    __shared__ u64 mks[4][12];
    __shared__ int pops[4][12];
    __shared__ int cnt4[4];
    __shared__ u16 idxs[4][768];
    __shared__ float4 ys[4][192];
    __shared__ float2 mi_sh[4];
    __shared__ double redd[12];

    int tid = threadIdx.x;
    int t = tid / 192;                 // 0..3 (3 waves per t-subgroup)
    int tg = tid % 192;                // col-group: cols 4tg..4tg+3

    if (tid < 48) {
        int tt = tid / 12, kw = tid % 12;
        u64 m = Am[((size_t)tt * 12 + kw) * BS_ + row];
        mks[tt][kw] = m;
        pops[tt][kw] = __popcll(m);
    }
    __syncthreads();
    if (tid < 48) {
        int tt = tid / 12, kw = tid % 12;
        int off = 0;
        for (int j = 0; j < kw; ++j) off += pops[tt][j];
        u64 m = mks[tt][kw];
        int kb0 = kw * 64;
        while (m) {
            int kb = __builtin_ctzll(m);
            m &= m - 1;
            idxs[tt][off++] = (u16)(kb0 + kb);
        }
        if (kw == 11) cnt4[tt] = off;
    }
    __syncthreads();

    int cn = cnt4[t];
    float y0 = 0.f, y1 = 0.f, y2 = 0.f, y3 = 0.f;
    const u16* il = idxs[t];
    #pragma unroll 8
    for (int i = 0; i < cn; ++i) {
        float4 w = Wv4[(size_t)il[i] * 192 + tg];
        y0 += w.x; y1 += w.y; y2 += w.z; y3 += w.w;
    }

    int lane = tid & 63;
    int wv_t = tg >> 6;
    double s = (double)y0 + (double)y1 + (double)y2 + (double)y3;
    #pragma unroll
    for (int o = 1; o < 64; o <<= 1) s += __shfl_xor(s, o, 64);
    if (lane == 0) redd[t * 3 + wv_t] = s;
    __syncthreads();
    double stot = redd[t * 3] + redd[t * 3 + 1] + redd[t * 3 + 2];
    float mean = (float)(stot / 768.0);
    float d0 = y0 - mean, d1 = y1 - mean, d2 = y2 - mean, d3 = y3 - mean;
    double q = (double)(d0*d0) + (double)(d1*d1) + (double)(d2*d2) + (double)(d3*d3);
    #pragma unroll
    for (int o = 1; o < 64; o <<= 1) q += __shfl_xor(q, o, 64);
    __syncthreads();
    if (lane == 0) redd[t * 3 + wv_t] = q;
    __syncthreads();
    double qtot = redd[t * 3] + redd[t * 3 + 1] + redd[t * 3 + 2];
    float var = (float)(qtot / 768.0);
    float inv = 1.0f / __fsqrt_rn(var + LN_EPS);

    ys[t][tg] = make_float4(y0, y1, y2, y3);
    if (tg == 0) mi_sh[t] = make_float2(mean, inv);
    __syncthreads();

    if (tid < 192) {
        float4 gd = ((const float4*)g)[tg];
        float4 bd = ((const float4*)bb)[tg];
        float4 yt[4];
        float2 mi[4];
        #pragma unroll
        for (int tt = 0; tt < 4; ++tt) { yt[tt] = ys[tt][tg]; mi[tt] = mi_sh[tt]; }
        uchar4 o4[4];
        #pragma unroll
        for (int j = 0; j < 4; ++j) {
            float gj = (j == 0) ? gd.x : (j == 1) ? gd.y : (j == 2) ? gd.z : gd.w;
            float bj = (j == 0) ? bd.x : (j == 1) ? bd.y : (j == 2) ? bd.z : bd.w;
            float v = 0.f;
            #pragma unroll
            for (int tt = 0; tt < 4; ++tt) {
                float yj = (j == 0) ? yt[tt].x : (j == 1) ? yt[tt].y : (j == 2) ? yt[tt].z : yt[tt].w;
                float d = yj - mi[tt].x;
                float yn = ((d * mi[tt].y) * gj) + bj;
                v += yn;
                bool sp = (v >= 1.0f);
                u8 sb = sp ? (u8)1 : (u8)0;
                if (j == 0) o4[tt].x = sb;
                if (j == 1) o4[tt].y = sb;
                if (j == 2) o4[tt].z = sb;
                if (j == 3) o4[tt].w = sb;
                if (sp) v = 0.f;
            }
        }
        #pragma unroll
        for (int tt = 0; tt < 4; ++tt)
            *(uchar4*)(Sp + ((size_t)tt * BS_ + row) * D_ + tg * 4) = o4[tt];
    }
}

// ---- QK column-dot over S (exact integer counts) ----
__global__ void k_qkred(const u8* __restrict__ Q, const u8* __restrict__ K,
                        float* __restrict__ QK) {
    int bid = blockIdx.x;           // 1024 blocks, 192 threads
    int sg = bid & 31, tb = bid >> 5;
    int tid = threadIdx.x;
    int c4 = tid * 4;
    size_t base = (size_t)tb * S_ * D_ + (size_t)sg * 32 * D_;
    int acc[4] = {0, 0, 0, 0};
    for (int s = 0; s < 32; ++s) {
        uchar4 q = *(const uchar4*)(Q + base + (size_t)s * D_ + c4);
        uchar4 k = *(const uchar4*)(K + base + (size_t)s * D_ + c4);
        acc[0] += q.x & k.x; acc[1] += q.y & k.y; acc[2] += q.z & k.z; acc[3] += q.w & k.w;
    }
    float* dst = QK + (size_t)tb * D_ + c4;
    #pragma unroll
    for (int j = 0; j < 4; ++j) atomicAdd(dst + j, (float)acc[j]);
}

// ---- IF over T on QK counts (integer-exact) ----
__global__ void k_qkif(const float* __restrict__ QK, u8* __restrict__ QKs) {
    int i = blockIdx.x * 256 + threadIdx.x;     // 24 blocks
    float v = 0.f;
    for (int t = 0; t < T_; ++t) {
        v += QK[t * (B_ * D_) + i];
        bool s = (v >= 1.0f);
        QKs[t * (B_ * D_) + i] = s ? 1 : 0;
        if (s) v = 0.f;
    }
}

// ---- QKV = V * QKs -> bf16 {0,1} ----
__global__ void k_qkv(const u8* __restrict__ V, const u8* __restrict__ QKs,
                      u16* __restrict__ O) {
    size_t e = ((size_t)blockIdx.x * 256 + threadIdx.x) * 4;    // 24576 blocks
    uchar4 v = *(const uchar4*)(V + e);
    size_t d = e % D_;
    size_t b = (e / ((size_t)S_ * D_)) % B_;
    size_t t = e / BSD_;
    uchar4 qk = *(const uchar4*)(QKs + t * (B_ * D_) + b * D_ + d);
    ushort4 o;
    o.x = (v.x & qk.x) ? 0x3F80 : 0;
    o.y = (v.y & qk.y) ? 0x3F80 : 0;
    o.z = (v.z & qk.z) ? 0x3F80 : 0;
    o.w = (v.w & qk.w) ? 0x3F80 : 0;
    *(ushort4*)(O + e) = o;
}

// ---- block reduction helper (final LN only; tolerance loose) ----
__device__ __forceinline__ float block_sum(float v, float* red) {
    #pragma unroll
    for (int o = 32; o > 0; o >>= 1) v += __shfl_down(v, o, 64);
    int lane = threadIdx.x & 63, w = threadIdx.x >> 6;
    __syncthreads();
    if (lane == 0) red[w] = v;
    __syncthreads();
    return (red[0] + red[1]) + (red[2] + red[3]);
}

__global__ __launch_bounds__(256)
void k_lnfinal(const float* __restrict__ Y, const float* __restrict__ g,
               const float* __restrict__ bt, float* __restrict__ out) {
    #pragma clang fp contract(off)
    __shared__ float red[4];
    size_t row = (size_t)blockIdx.x * D_;       // 32768 rows
    int tid = threadIdx.x;
    float y[3];
    float s = 0.f;
    #pragma unroll
    for (int j = 0; j < 3; ++j) { y[j] = Y[row + tid + j * 256]; s += y[j]; }
    float mean = block_sum(s, red) / 768.0f;
    float q = 0.f;
    #pragma unroll
    for (int j = 0; j < 3; ++j) { float d = y[j] - mean; q += d * d; }
    float var = block_sum(q, red) / 768.0f;
    float inv = 1.0f / __fsqrt_rn(var + LN_EPS);
    #pragma unroll
    for (int j = 0; j < 3; ++j) {
        int c = tid + j * 256;
        out[row + c] = (y[j] - mean) * inv * g[c] + bt[c];
    }
}

extern "C" void kernel_launch(void* const* d_in, const int* in_sizes, int n_in,
                              void* d_out, int out_size, void* d_ws, size_t ws_size,
                              hipStream_t stream) {
    const float* x  = (const float*)d_in[0];
    const float* wq = (const float*)d_in[1];
    const float* wk = (const float*)d_in[2];
    const float* wv = (const float*)d_in[3];
    const float* wo = (const float*)d_in[4];
    const float* gq = (const float*)d_in[5];
    const float* bq = (const float*)d_in[6];
    const float* gk = (const float*)d_in[7];
    const float* bk = (const float*)d_in[8];
    const float* gv = (const float*)d_in[9];
    const float* bv = (const float*)d_in[10];
    const float* go = (const float*)d_in[11];
    const float* bo = (const float*)d_in[12];
    float* out = (float*)d_out;

    char* ws = (char*)d_ws;
    size_t off = 0;
    auto alloc = [&](size_t bytes) -> void* {
        void* p = ws + off;
        off += (bytes + 255) & ~(size_t)255;
        return p;
    };
    u64* Am    = (u64*)alloc((size_t)T_ * 12 * BS_ * 8);     // 3 MB bitmasks
    u16* Ab    = (u16*)alloc((size_t)M_ * D_ * 2);           // 48 MB bf16 spikes / reused for QKV
    float* Y   = (float*)alloc((size_t)M_ * D_ * 4);         // 96 MB GEMM out
    u8* Qs     = (u8*)alloc((size_t)M_ * D_);
    u8* Ks     = (u8*)alloc((size_t)M_ * D_);
    u8* Vs     = (u8*)alloc((size_t)M_ * D_);
    u16* Whi   = (u16*)alloc((size_t)3 * D_ * D_ * 2);
    u16* Wlo   = (u16*)alloc((size_t)3 * D_ * D_ * 2);
    u16* Wo    = (u16*)alloc((size_t)D_ * D_ * 2);
    float* QK  = (float*)alloc((size_t)T_ * B_ * D_ * 4);
    u8* QKs    = (u8*)alloc((size_t)T_ * B_ * D_);
    int* rowlist = (int*)alloc((size_t)3 * BS_ * 4);
    int* cnt   = (int*)alloc(256);

    hipMemsetAsync(QK, 0, (size_t)T_ * B_ * D_ * 4, stream);
    hipMemsetAsync(cnt, 0, 12, stream);

    // 1. IF over x -> bitmasks + bf16 spikes (bit-exact)
    k_if_mask<<<BS_, 768, 0, stream>>>(x, Am, Ab);
    // 2. weight conversion
    k_wconv<<<(4 * D_ * D_) / 256, 256, 0, stream>>>(wq, wk, wv, wo, Whi, Wlo, Wo);
    // 3. Q/K/V: split-bf16 MFMA GEMM (BK=64, single pass hi+lo) + f64-LN + IF + flags
    const int ntn = D_ / 128;                           // 6
    const int gemm_grid = (M_ / 128) * ntn;             // 1536 (%8==0 for XCD swizzle)
    k_gemm<2><<<gemm_grid, 256, 0, stream>>>(Ab, Whi + 0 * D_ * D_, Wlo + 0 * D_ * D_, Y, ntn, D_);
    k_lnif<<<BS_ / 4, 256, 0, stream>>>(Y, gq, bq, Qs, rowlist, cnt, 0);
    k_gemm<2><<<gemm_grid, 256, 0, stream>>>(Ab, Whi + 1 * D_ * D_, Wlo + 1 * D_ * D_, Y, ntn, D_);
    k_lnif<<<BS_ / 4, 256, 0, stream>>>(Y, gk, bk, Ks, rowlist, cnt, 1);
    k_gemm<2><<<gemm_grid, 256, 0, stream>>>(Ab, Whi + 2 * D_ * D_, Wlo + 2 * D_ * D_, Y, ntn, D_);
    k_lnif<<<BS_ / 4, 256, 0, stream>>>(Y, gv, bv, Vs, rowlist, cnt, 2);
    // 3b. exact row repair (branchless per-(row,t) walks, t parallel)
    k_repairT<<<dim3(BS_, 3), 768, 0, stream>>>(Am, wq, wk, wv, gq, bq, gk, bk, gv, bv,
                                                Qs, Ks, Vs, rowlist, cnt);
    // 4. QK column-dot + IF (integer-exact)
    k_qkred<<<T_ * B_ * 32, 192, 0, stream>>>(Qs, Ks, QK);
    k_qkif<<<(B_ * D_) / 256, 256, 0, stream>>>(QK, QKs);
    // 5. QKV = V * QKs -> bf16 (reuse Ab)
    k_qkv<<<(M_ * D_) / 4 / 256, 256, 0, stream>>>(Vs, QKs, Ab);
    // 6. output projection (bf16 MFMA; loose tolerance) + final LN
    k_gemm<1><<<gemm_grid, 256, 0, stream>>>(Ab, Wo, Wo, Y, ntn, D_);
    k_lnfinal<<<M_, 256, 0, stream>>>(Y, go, bo, out);
}